// Round 3
// baseline (1475.693 us; speedup 1.0000x reference)
//
#include <hip/hip_runtime.h>

#define N_NODES 100000
#define N_EDGES 3200000
static constexpr int NB = (N_NODES + 255) / 256;  // 391

__device__ __forceinline__ float bf2f(unsigned short u) {
  return __uint_as_float(((unsigned)u) << 16);
}
__device__ __forceinline__ unsigned short f2bf(float f) {
  unsigned u = __float_as_uint(f);
  u += 0x7fffu + ((u >> 16) & 1u);
  return (unsigned short)(u >> 16);
}

// ---------------- dtype detection ----------------
// flag=1: float arrays are bf16 (u16). flag=0: they are fp32.
// Even-index u16s of an fp32 buffer are mantissa low-halves -> log-uniform
// garbage when decoded as bf16 (~7% in [1e-4,10]); of a bf16 buffer they are
// genuine N(0,1) values (~100% in range).

__global__ void k_detect(const unsigned short* __restrict__ xu, int* __restrict__ flag) {
  __shared__ int cnt;
  if (threadIdx.x == 0) cnt = 0;
  __syncthreads();
  int c = 0;
  for (int i = threadIdx.x; i < 4096; i += 256) {
    float v = fabsf(bf2f(xu[2 * i]));
    if (v >= 1e-4f && v <= 10.f) c++;
  }
  atomicAdd(&cnt, c);
  __syncthreads();
  if (threadIdx.x == 0) *flag = (cnt > 2048) ? 1 : 0;
}

// ---------------- canonicalize inputs to bf16 ----------------

__global__ __launch_bounds__(256) void k_cvt_x(const void* __restrict__ x,
                                               unsigned short* __restrict__ xb,
                                               const int* __restrict__ flag) {
  int i = blockIdx.x * 256 + threadIdx.x;
  if (i >= N_NODES * 64) return;
  if (*flag)
    xb[i] = ((const unsigned short*)x)[i];
  else
    xb[i] = f2bf(((const float*)x)[i]);
}

struct CvtArgs {
  const void* src[24];
  int dstoff[24];
  int n[24];
};

__global__ void k_cvt_w(CvtArgs a, unsigned short* __restrict__ wb,
                        const int* __restrict__ flag) {
  int b = blockIdx.x;
  const void* s = a.src[b];
  int n = a.n[b];
  unsigned short* d = wb + a.dstoff[b];
  int isbf = *flag;
  for (int i = threadIdx.x; i < n; i += 256)
    d[i] = isbf ? ((const unsigned short*)s)[i] : f2bf(((const float*)s)[i]);
}

// ---------------- CSR build ----------------

__global__ void k_zero(int* p, int n) {
  int i = blockIdx.x * 256 + threadIdx.x;
  if (i < n) p[i] = 0;
}

__global__ void k_hist(const int* __restrict__ dsts, int* __restrict__ deg) {
  int e = blockIdx.x * 256 + threadIdx.x;
  if (e < N_EDGES) atomicAdd(&deg[dsts[e]], 1);
}

__global__ void k_scan1(const int* __restrict__ deg, int* __restrict__ bsum) {
  __shared__ int s[256];
  int i = blockIdx.x * 256 + threadIdx.x;
  int v = (i < N_NODES) ? deg[i] : 0;
  s[threadIdx.x] = v;
  __syncthreads();
  for (int o = 128; o > 0; o >>= 1) {
    if (threadIdx.x < o) s[threadIdx.x] += s[threadIdx.x + o];
    __syncthreads();
  }
  if (threadIdx.x == 0) bsum[blockIdx.x] = s[0];
}

__global__ void k_scan2(const int* __restrict__ bsum, int* __restrict__ bpref,
                        int* __restrict__ off_last) {
  __shared__ int s[512];
  int t = threadIdx.x;
  int v = (t < NB) ? bsum[t] : 0;
  s[t] = v;
  __syncthreads();
  for (int o = 1; o < 512; o <<= 1) {
    int u = (t >= o) ? s[t - o] : 0;
    __syncthreads();
    s[t] += u;
    __syncthreads();
  }
  if (t < NB) bpref[t] = s[t] - v;      // exclusive
  if (t == NB - 1) off_last[0] = s[t];  // total = E
}

__global__ void k_scan3(const int* __restrict__ deg, const int* __restrict__ bpref,
                        int* __restrict__ off, int* __restrict__ cursor) {
  __shared__ int s[256];
  int t = threadIdx.x;
  int i = blockIdx.x * 256 + t;
  int v = (i < N_NODES) ? deg[i] : 0;
  s[t] = v;
  __syncthreads();
  for (int o = 1; o < 256; o <<= 1) {
    int u = (t >= o) ? s[t - o] : 0;
    __syncthreads();
    s[t] += u;
    __syncthreads();
  }
  if (i < N_NODES) {
    int e = bpref[blockIdx.x] + s[t] - v;
    off[i] = e;
    cursor[i] = e;
  }
}

__global__ void k_scatter(const int* __restrict__ srcs, const int* __restrict__ dsts,
                          int* __restrict__ cursor, int* __restrict__ csr) {
  int e = blockIdx.x * 256 + threadIdx.x;
  if (e < N_EDGES) {
    int p = atomicAdd(&cursor[dsts[e]], 1);
    csr[p] = srcs[e];
  }
}

// ---------------- K,V projection: wave per row, VALU ----------------
// KV32[r*64+l] = bf16(k_l) | bf16(v_l)<<16

__global__ __launch_bounds__(256) void k_gemmkv(
    const unsigned short* __restrict__ hin,
    const unsigned short* __restrict__ Wk, const unsigned short* __restrict__ bk,
    const unsigned short* __restrict__ Wv, const unsigned short* __restrict__ bv,
    unsigned* __restrict__ KV32) {
  int r = blockIdx.x * 4 + (threadIdx.x >> 6);
  int lane = threadIdx.x & 63;
  float hv = bf2f(hin[(size_t)r * 64 + lane]);
  float ka = bf2f(bk[lane]);
  float va = bf2f(bv[lane]);
  for (int k = 0; k < 64; ++k) {
    float hk = __shfl(hv, k, 64);
    ka += hk * bf2f(Wk[k * 64 + lane]);
    va += hk * bf2f(Wv[k * 64 + lane]);
  }
  KV32[(size_t)r * 64 + lane] = (unsigned)f2bf(ka) | ((unsigned)f2bf(va) << 16);
}

// ---------------- edge pass, C=64: wave per dst, lazy q/s, online softmax ----------------

template <bool RES>
__global__ __launch_bounds__(256) void k_edge64(
    const int* __restrict__ off, const int* __restrict__ csr,
    const unsigned short* __restrict__ hin,
    const unsigned short* __restrict__ Wq, const unsigned short* __restrict__ bq,
    const unsigned short* __restrict__ Ws, const unsigned short* __restrict__ bs,
    const unsigned* __restrict__ KV32,
    unsigned short* __restrict__ hout) {
  int wid = blockIdx.x * 4 + (threadIdx.x >> 6);  // dst node
  int lane = threadIdx.x & 63;
  int base = off[wid];
  int deg = off[wid + 1] - base;
  float hv = bf2f(hin[(size_t)wid * 64 + lane]);
  // lazy q, skip: q_l = sum_k h_k * Wq[k][l] + bq[l]  (f32 accumulation)
  float q = bf2f(bq[lane]);
  float sk = bf2f(bs[lane]);
  for (int k = 0; k < 64; ++k) {
    float hk = __shfl(hv, k, 64);
    q += hk * bf2f(Wq[k * 64 + lane]);
    sk += hk * bf2f(Ws[k * 64 + lane]);
  }
  float m = -1e30f, ssum = 0.f, acc = 0.f;
  for (int j0 = 0; j0 < deg; j0 += 64) {
    int mysrc = (j0 + lane < deg) ? csr[base + j0 + lane] : 0;
    int cnt = min(64, deg - j0);
    for (int jj = 0; jj < cnt; ++jj) {
      int src = __shfl(mysrc, jj, 64);
      unsigned kv = KV32[(size_t)src * 64 + lane];  // (k_l | v_l<<16)
      float kk = __uint_as_float(kv << 16);
      float vv = __uint_as_float(kv & 0xffff0000u);
      float t = q * kk;
      t += __shfl_xor(t, 32, 64);
      t += __shfl_xor(t, 16, 64);
      t += __shfl_xor(t, 8, 64);
      t += __shfl_xor(t, 4, 64);
      t += __shfl_xor(t, 2, 64);
      t += __shfl_xor(t, 1, 64);
      float score = fminf(fmaxf(t * 0.125f, -60.f), 60.f);  // /sqrt(64), clamped
      float mn = fmaxf(m, score);
      float corr = __expf(m - mn);
      float al = __expf(score - mn);
      ssum = ssum * corr + al;
      acc = acc * corr + al * vv;
      m = mn;
    }
  }
  float val = acc / (ssum + 1e-16f) + sk;
  if (RES) val += hv;
  hout[(size_t)wid * 64 + lane] = f2bf(tanhf(val));
}

// ---------------- layer 3 projections (C=3): thread per node ----------------

__global__ __launch_bounds__(256) void k_gemm3(
    const unsigned short* __restrict__ hin,
    const unsigned short* __restrict__ Wq, const unsigned short* __restrict__ bq,
    const unsigned short* __restrict__ Wk, const unsigned short* __restrict__ bk,
    const unsigned short* __restrict__ Wv, const unsigned short* __restrict__ bv,
    const unsigned short* __restrict__ Ws, const unsigned short* __restrict__ bs,
    float* __restrict__ Q3, float* __restrict__ S3, uint4* __restrict__ KV3) {
  int d = blockIdx.x * 256 + threadIdx.x;
  if (d >= N_NODES) return;
  float q[3], kk[3], vv[3], ss[3];
  for (int c = 0; c < 3; ++c) {
    q[c] = bf2f(bq[c]);
    kk[c] = bf2f(bk[c]);
    vv[c] = bf2f(bv[c]);
    ss[c] = bf2f(bs[c]);
  }
  for (int j = 0; j < 64; ++j) {
    float hj = bf2f(hin[(size_t)d * 64 + j]);
    for (int c = 0; c < 3; ++c) {
      q[c] += hj * bf2f(Wq[j * 3 + c]);
      kk[c] += hj * bf2f(Wk[j * 3 + c]);
      vv[c] += hj * bf2f(Wv[j * 3 + c]);
      ss[c] += hj * bf2f(Ws[j * 3 + c]);
    }
  }
  for (int c = 0; c < 3; ++c) {
    Q3[d * 4 + c] = q[c];
    S3[d * 4 + c] = ss[c];
  }
  uint4 pk;
  pk.x = (unsigned)f2bf(kk[0]) | ((unsigned)f2bf(vv[0]) << 16);
  pk.y = (unsigned)f2bf(kk[1]) | ((unsigned)f2bf(vv[1]) << 16);
  pk.z = (unsigned)f2bf(kk[2]) | ((unsigned)f2bf(vv[2]) << 16);
  pk.w = 0;
  KV3[d] = pk;
}

// ---------------- edge pass, C=3: thread per dst + final output ----------------

__global__ __launch_bounds__(256) void k_edge3(
    const int* __restrict__ off, const int* __restrict__ csr,
    const float* __restrict__ Q3, const float* __restrict__ S3,
    const uint4* __restrict__ KV3, const void* __restrict__ noise,
    void* __restrict__ out, const int* __restrict__ flag) {
  int d = blockIdx.x * 256 + threadIdx.x;
  if (d >= N_NODES) return;
  int base = off[d];
  int deg = off[d + 1] - base;
  float q0 = Q3[d * 4], q1 = Q3[d * 4 + 1], q2 = Q3[d * 4 + 2];
  float m = -1e30f, ssum = 0.f, a0 = 0.f, a1 = 0.f, a2 = 0.f;
  const float isq = 0.57735026919f;  // 1/sqrt(3)
  for (int j = 0; j < deg; ++j) {
    int src = csr[base + j];
    uint4 kv = KV3[src];
    float k0 = __uint_as_float(kv.x << 16), v0 = __uint_as_float(kv.x & 0xffff0000u);
    float k1 = __uint_as_float(kv.y << 16), v1 = __uint_as_float(kv.y & 0xffff0000u);
    float k2 = __uint_as_float(kv.z << 16), v2 = __uint_as_float(kv.z & 0xffff0000u);
    float sc = fminf(fmaxf((q0 * k0 + q1 * k1 + q2 * k2) * isq, -60.f), 60.f);
    float mn = fmaxf(m, sc);
    float corr = __expf(m - mn);
    float al = __expf(sc - mn);
    ssum = ssum * corr + al;
    a0 = a0 * corr + al * v0;
    a1 = a1 * corr + al * v1;
    a2 = a2 * corr + al * v2;
    m = mn;
  }
  float inv = 1.f / (ssum + 1e-16f);
  int isbf = *flag;
  float n0, n1, n2;
  if (isbf) {
    const unsigned short* nu = (const unsigned short*)noise;
    n0 = bf2f(nu[d * 3 + 0]);
    n1 = bf2f(nu[d * 3 + 1]);
    n2 = bf2f(nu[d * 3 + 2]);
  } else {
    const float* nf = (const float*)noise;
    n0 = nf[d * 3 + 0];
    n1 = nf[d * 3 + 1];
    n2 = nf[d * 3 + 2];
  }
  float r0 = a0 * inv + S3[d * 4 + 0] + 0.1f * n0;
  float r1 = a1 * inv + S3[d * 4 + 1] + 0.1f * n1;
  float r2 = a2 * inv + S3[d * 4 + 2] + 0.1f * n2;
  if (isbf) {
    unsigned short* ou = (unsigned short*)out;
    ou[d * 3 + 0] = f2bf(r0);
    ou[d * 3 + 1] = f2bf(r1);
    ou[d * 3 + 2] = f2bf(r2);
  } else {
    float* of = (float*)out;
    of[d * 3 + 0] = r0;
    of[d * 3 + 1] = r1;
    of[d * 3 + 2] = r2;
  }
}

// ---------------- launch ----------------

extern "C" void kernel_launch(void* const* d_in, const int* in_sizes, int n_in,
                              void* d_out, int out_size, void* d_ws, size_t ws_size,
                              hipStream_t stream) {
  const int* ei = (const int*)d_in[1];
  const int* srcs = ei;
  const int* dsts = ei + N_EDGES;

  // Workspace layout (NEED = 51668480 B ~ 51.7 MB; round 2 proved ws >= 51.6 MB):
  //   off @0 (0.4MB) | csr @400128 (12.8MB) | h/xb @13200128 (12.8MB bf16)
  //   KV @26000128 (25.6MB; aliases CSR scratch pre-layer-1, Q3/S3/KV3 in layer 3)
  //   wb @51600128 (68KB bf16 weights) | flag @51668352
  char* w = (char*)d_ws;
  int* off = (int*)w;
  int* csr = (int*)(w + 400128);
  unsigned short* h = (unsigned short*)(w + 13200128);
  char* kvbase = w + 26000128;
  unsigned* KV = (unsigned*)kvbase;
  int* deg = (int*)kvbase;
  int* cursor = (int*)(kvbase + 524288);
  int* bsum = (int*)(kvbase + 1048576);
  int* bpref = (int*)(kvbase + 1056768);
  float* Q3 = (float*)kvbase;
  float* S3 = (float*)(kvbase + 2097152);
  uint4* KV3 = (uint4*)(kvbase + 4194304);
  unsigned short* wb = (unsigned short*)(w + 51600128);
  int* flag = (int*)(w + 51668352);
  const size_t NEED = 51668480;
  if (ws_size < NEED) return;  // diagnosable: leaves d_out zeroed (absmax ~1.41)

  // Canonical bf16 weight pointers inside wb
  unsigned short *Wb[3][4], *Bb[3][4];
  CvtArgs ca;
  {
    int o = 0, idx = 0;
    for (int l = 0; l < 3; ++l) {
      int dout = (l == 2) ? 3 : 64;
      for (int p = 0; p < 4; ++p) {
        ca.src[idx] = d_in[3 + l * 8 + p * 2];
        ca.dstoff[idx] = o;
        ca.n[idx] = 64 * dout;
        Wb[l][p] = wb + o;
        o += 64 * dout;
        idx++;
        ca.src[idx] = d_in[3 + l * 8 + p * 2 + 1];
        ca.dstoff[idx] = o;
        ca.n[idx] = dout;
        Bb[l][p] = wb + o;
        o += dout;
        idx++;
      }
    }
  }

  k_detect<<<1, 256, 0, stream>>>((const unsigned short*)d_in[0], flag);
  k_cvt_w<<<24, 256, 0, stream>>>(ca, wb, flag);
  k_cvt_x<<<N_NODES * 64 / 256, 256, 0, stream>>>(d_in[0], h, flag);

  // CSR build (reused by all 3 layers)
  k_zero<<<NB, 256, 0, stream>>>(deg, N_NODES);
  k_hist<<<N_EDGES / 256, 256, 0, stream>>>(dsts, deg);
  k_scan1<<<NB, 256, 0, stream>>>(deg, bsum);
  k_scan2<<<1, 512, 0, stream>>>(bsum, bpref, off + N_NODES);
  k_scan3<<<NB, 256, 0, stream>>>(deg, bpref, off, cursor);
  k_scatter<<<N_EDGES / 256, 256, 0, stream>>>(srcs, dsts, cursor, csr);

  const int gw = N_NODES / 4;  // 25000 blocks, 4 waves each
  // layer 1: input = h (canonical x), output h in-place (row-local)
  k_gemmkv<<<gw, 256, 0, stream>>>(h, Wb[0][1], Bb[0][1], Wb[0][2], Bb[0][2], KV);
  k_edge64<false><<<gw, 256, 0, stream>>>(off, csr, h, Wb[0][0], Bb[0][0],
                                          Wb[0][3], Bb[0][3], KV, h);
  // layer 2: in-place again
  k_gemmkv<<<gw, 256, 0, stream>>>(h, Wb[1][1], Bb[1][1], Wb[1][2], Bb[1][2], KV);
  k_edge64<true><<<gw, 256, 0, stream>>>(off, csr, h, Wb[1][0], Bb[1][0],
                                         Wb[1][3], Bb[1][3], KV, h);
  // layer 3: projections then edge pass + noise + output
  k_gemm3<<<NB, 256, 0, stream>>>(h, Wb[2][0], Bb[2][0], Wb[2][1], Bb[2][1],
                                  Wb[2][2], Bb[2][2], Wb[2][3], Bb[2][3], Q3, S3, KV3);
  k_edge3<<<NB, 256, 0, stream>>>(off, csr, Q3, S3, KV3, d_in[2], d_out, flag);
}

// Round 4
// 1469.950 us; speedup vs baseline: 1.0039x; 1.0039x over previous
//
#include <hip/hip_runtime.h>

#define N_NODES 100000
#define N_EDGES 3200000
static constexpr int NB = (N_NODES + 255) / 256;  // 391

__device__ __forceinline__ float bf2f(unsigned short u) {
  return __uint_as_float(((unsigned)u) << 16);
}
__device__ __forceinline__ unsigned short f2bf(float f) {
  unsigned u = __float_as_uint(f);
  u += 0x7fffu + ((u >> 16) & 1u);
  return (unsigned short)(u >> 16);
}
__device__ __forceinline__ float lo16(unsigned u) { return __uint_as_float(u << 16); }
__device__ __forceinline__ float hi16(unsigned u) { return __uint_as_float(u & 0xffff0000u); }

// ---------------- dtype detection (flag=1: bf16 storage, 0: fp32) ----------------

__global__ void k_detect(const unsigned short* __restrict__ xu, int* __restrict__ flag) {
  __shared__ int cnt;
  if (threadIdx.x == 0) cnt = 0;
  __syncthreads();
  int c = 0;
  for (int i = threadIdx.x; i < 4096; i += 256) {
    float v = fabsf(bf2f(xu[2 * i]));
    if (v >= 1e-4f && v <= 10.f) c++;
  }
  atomicAdd(&cnt, c);
  __syncthreads();
  if (threadIdx.x == 0) *flag = (cnt > 2048) ? 1 : 0;
}

// ---------------- canonicalize inputs to bf16 ----------------

__global__ __launch_bounds__(256) void k_cvt_x(const void* __restrict__ x,
                                               unsigned short* __restrict__ xb,
                                               const int* __restrict__ flag) {
  int i = blockIdx.x * 256 + threadIdx.x;
  if (i >= N_NODES * 64) return;
  if (*flag)
    xb[i] = ((const unsigned short*)x)[i];
  else
    xb[i] = f2bf(((const float*)x)[i]);
}

struct CvtArgs {
  const void* src[24];
  int dstoff[24];
  int n[24];
};

__global__ void k_cvt_w(CvtArgs a, unsigned short* __restrict__ wb,
                        const int* __restrict__ flag) {
  int b = blockIdx.x;
  const void* s = a.src[b];
  int n = a.n[b];
  unsigned short* d = wb + a.dstoff[b];
  int isbf = *flag;
  for (int i = threadIdx.x; i < n; i += 256)
    d[i] = isbf ? ((const unsigned short*)s)[i] : f2bf(((const float*)s)[i]);
}

// ---------------- CSR build ----------------

__global__ void k_zero(int* p, int n) {
  int i = blockIdx.x * 256 + threadIdx.x;
  if (i < n) p[i] = 0;
}

__global__ void k_hist(const int* __restrict__ dsts, int* __restrict__ deg) {
  int e = blockIdx.x * 256 + threadIdx.x;
  if (e < N_EDGES) atomicAdd(&deg[dsts[e]], 1);
}

__global__ void k_scan1(const int* __restrict__ deg, int* __restrict__ bsum) {
  __shared__ int s[256];
  int i = blockIdx.x * 256 + threadIdx.x;
  int v = (i < N_NODES) ? deg[i] : 0;
  s[threadIdx.x] = v;
  __syncthreads();
  for (int o = 128; o > 0; o >>= 1) {
    if (threadIdx.x < o) s[threadIdx.x] += s[threadIdx.x + o];
    __syncthreads();
  }
  if (threadIdx.x == 0) bsum[blockIdx.x] = s[0];
}

__global__ void k_scan2(const int* __restrict__ bsum, int* __restrict__ bpref,
                        int* __restrict__ off_last) {
  __shared__ int s[512];
  int t = threadIdx.x;
  int v = (t < NB) ? bsum[t] : 0;
  s[t] = v;
  __syncthreads();
  for (int o = 1; o < 512; o <<= 1) {
    int u = (t >= o) ? s[t - o] : 0;
    __syncthreads();
    s[t] += u;
    __syncthreads();
  }
  if (t < NB) bpref[t] = s[t] - v;
  if (t == NB - 1) off_last[0] = s[t];
}

__global__ void k_scan3(const int* __restrict__ deg, const int* __restrict__ bpref,
                        int* __restrict__ off, int* __restrict__ cursor) {
  __shared__ int s[256];
  int t = threadIdx.x;
  int i = blockIdx.x * 256 + t;
  int v = (i < N_NODES) ? deg[i] : 0;
  s[t] = v;
  __syncthreads();
  for (int o = 1; o < 256; o <<= 1) {
    int u = (t >= o) ? s[t - o] : 0;
    __syncthreads();
    s[t] += u;
    __syncthreads();
  }
  if (i < N_NODES) {
    int e = bpref[blockIdx.x] + s[t] - v;
    off[i] = e;
    cursor[i] = e;
  }
}

__global__ void k_scatter(const int* __restrict__ srcs, const int* __restrict__ dsts,
                          int* __restrict__ cursor, int* __restrict__ csr) {
  int e = blockIdx.x * 256 + threadIdx.x;
  if (e < N_EDGES) {
    int p = atomicAdd(&cursor[dsts[e]], 1);
    csr[p] = srcs[e];
  }
}

// ---------------- K,V projection: wave per row -> separate K/V tables ----------------

__global__ __launch_bounds__(256) void k_gemmkv(
    const unsigned short* __restrict__ hin,
    const unsigned short* __restrict__ Wk, const unsigned short* __restrict__ bk,
    const unsigned short* __restrict__ Wv, const unsigned short* __restrict__ bv,
    unsigned short* __restrict__ Kt, unsigned short* __restrict__ Vt) {
  int r = blockIdx.x * 4 + (threadIdx.x >> 6);
  int lane = threadIdx.x & 63;
  float hv = bf2f(hin[(size_t)r * 64 + lane]);
  float ka = bf2f(bk[lane]);
  float va = bf2f(bv[lane]);
  for (int k = 0; k < 64; ++k) {
    float hk = __shfl(hv, k, 64);
    ka += hk * bf2f(Wk[k * 64 + lane]);
    va += hk * bf2f(Wv[k * 64 + lane]);
  }
  Kt[(size_t)r * 64 + lane] = f2bf(ka);
  Vt[(size_t)r * 64 + lane] = f2bf(va);
}

// ---------------- edge pass, C=64 ----------------
// Wave per dst. Per 64-edge batch: phase 1 = lane-per-edge score (q broadcast
// from LDS, K row gathered per lane, no cross-lane ops per edge); batch-level
// softmax butterfly; phase 2 = dim-per-lane V aggregation (alpha/src via
// register shfl, coalesced V-row loads, independent FMA chains).

template <bool RES>
__global__ __launch_bounds__(256) void k_edge64(
    const int* __restrict__ off, const int* __restrict__ csr,
    const unsigned short* __restrict__ hin,
    const unsigned short* __restrict__ Wq, const unsigned short* __restrict__ bq,
    const unsigned short* __restrict__ Ws, const unsigned short* __restrict__ bs,
    const unsigned short* __restrict__ Kt, const unsigned short* __restrict__ Vt,
    unsigned short* __restrict__ hout) {
  __shared__ float qs[4][64];
  int w = threadIdx.x >> 6;
  int lane = threadIdx.x & 63;
  int wid = blockIdx.x * 4 + w;
  int base = off[wid];
  int deg = off[wid + 1] - base;
  float hv = bf2f(hin[(size_t)wid * 64 + lane]);
  // projection: q_l, s_l (dim-per-lane, f32)
  float q = bf2f(bq[lane]);
  float sk = bf2f(bs[lane]);
  for (int k = 0; k < 64; ++k) {
    float hk = __shfl(hv, k, 64);
    q += hk * bf2f(Wq[k * 64 + lane]);
    sk += hk * bf2f(Ws[k * 64 + lane]);
  }
  qs[w][lane] = q;  // wave-local write->read; lgkmcnt ordering within wave

  float m = -1e30f, ssum = 0.f, acc0 = 0.f, acc1 = 0.f;
  const float4* qv = (const float4*)qs[w];

  for (int j0 = 0; j0 < deg; j0 += 64) {
    int cnt = min(64, deg - j0);
    int src = csr[base + ((lane < cnt) ? (j0 + lane) : 0)];
    // ---- phase 1: my edge's score ----
    const uint4* kp = (const uint4*)(Kt + (size_t)src * 64);
    float d0 = 0.f, d1 = 0.f, d2 = 0.f, d3 = 0.f;
#pragma unroll
    for (int i = 0; i < 8; ++i) {
      uint4 kk = kp[i];
      float4 qa = qv[2 * i];
      float4 qb = qv[2 * i + 1];
      d0 += qa.x * lo16(kk.x); d1 += qa.y * hi16(kk.x);
      d2 += qa.z * lo16(kk.y); d3 += qa.w * hi16(kk.y);
      d0 += qb.x * lo16(kk.z); d1 += qb.y * hi16(kk.z);
      d2 += qb.z * lo16(kk.w); d3 += qb.w * hi16(kk.w);
    }
    float sc = ((d0 + d1) + (d2 + d3)) * 0.125f;  // /sqrt(64)
    sc = fminf(fmaxf(sc, -60.f), 60.f);
    if (lane >= cnt) sc = -1e30f;
    // ---- batch softmax ----
    float bm = sc;
    bm = fmaxf(bm, __shfl_xor(bm, 32, 64));
    bm = fmaxf(bm, __shfl_xor(bm, 16, 64));
    bm = fmaxf(bm, __shfl_xor(bm, 8, 64));
    bm = fmaxf(bm, __shfl_xor(bm, 4, 64));
    bm = fmaxf(bm, __shfl_xor(bm, 2, 64));
    bm = fmaxf(bm, __shfl_xor(bm, 1, 64));
    float mn = fmaxf(m, bm);
    float al = __expf(sc - mn);  // inactive lanes -> 0
    float bsum = al;
    bsum += __shfl_xor(bsum, 32, 64);
    bsum += __shfl_xor(bsum, 16, 64);
    bsum += __shfl_xor(bsum, 8, 64);
    bsum += __shfl_xor(bsum, 4, 64);
    bsum += __shfl_xor(bsum, 2, 64);
    bsum += __shfl_xor(bsum, 1, 64);
    float corr = __expf(m - mn);
    ssum = ssum * corr + bsum;
    acc0 *= corr;
    acc1 *= corr;
    m = mn;
    // ---- phase 2: dim-per-lane aggregation ----
    int jj = 0;
    for (; jj + 1 < cnt; jj += 2) {
      int sA = __shfl(src, jj, 64);
      int sB = __shfl(src, jj + 1, 64);
      float aA = __shfl(al, jj, 64);
      float aB = __shfl(al, jj + 1, 64);
      float vA = bf2f(Vt[(size_t)sA * 64 + lane]);
      float vB = bf2f(Vt[(size_t)sB * 64 + lane]);
      acc0 += aA * vA;
      acc1 += aB * vB;
    }
    if (jj < cnt) {
      int sA = __shfl(src, jj, 64);
      float aA = __shfl(al, jj, 64);
      acc0 += aA * bf2f(Vt[(size_t)sA * 64 + lane]);
    }
  }
  float val = (acc0 + acc1) / (ssum + 1e-16f) + sk;
  if (RES) val += hv;
  hout[(size_t)wid * 64 + lane] = f2bf(tanhf(val));
}

// ---------------- layer 3 projections (C=3): thread per node ----------------

__global__ __launch_bounds__(256) void k_gemm3(
    const unsigned short* __restrict__ hin,
    const unsigned short* __restrict__ Wq, const unsigned short* __restrict__ bq,
    const unsigned short* __restrict__ Wk, const unsigned short* __restrict__ bk,
    const unsigned short* __restrict__ Wv, const unsigned short* __restrict__ bv,
    const unsigned short* __restrict__ Ws, const unsigned short* __restrict__ bs,
    float* __restrict__ Q3, float* __restrict__ S3, uint4* __restrict__ KV3) {
  int d = blockIdx.x * 256 + threadIdx.x;
  if (d >= N_NODES) return;
  float q[3], kk[3], vv[3], ss[3];
  for (int c = 0; c < 3; ++c) {
    q[c] = bf2f(bq[c]);
    kk[c] = bf2f(bk[c]);
    vv[c] = bf2f(bv[c]);
    ss[c] = bf2f(bs[c]);
  }
  for (int j = 0; j < 64; ++j) {
    float hj = bf2f(hin[(size_t)d * 64 + j]);
    for (int c = 0; c < 3; ++c) {
      q[c] += hj * bf2f(Wq[j * 3 + c]);
      kk[c] += hj * bf2f(Wk[j * 3 + c]);
      vv[c] += hj * bf2f(Wv[j * 3 + c]);
      ss[c] += hj * bf2f(Ws[j * 3 + c]);
    }
  }
  for (int c = 0; c < 3; ++c) {
    Q3[d * 4 + c] = q[c];
    S3[d * 4 + c] = ss[c];
  }
  uint4 pk;
  pk.x = (unsigned)f2bf(kk[0]) | ((unsigned)f2bf(vv[0]) << 16);
  pk.y = (unsigned)f2bf(kk[1]) | ((unsigned)f2bf(vv[1]) << 16);
  pk.z = (unsigned)f2bf(kk[2]) | ((unsigned)f2bf(vv[2]) << 16);
  pk.w = 0;
  KV3[d] = pk;
}

// ---------------- edge pass, C=3: two-pass (no serial exp-rescale chain) ----------------

__global__ __launch_bounds__(256) void k_edge3(
    const int* __restrict__ off, const int* __restrict__ csr,
    const float* __restrict__ Q3, const float* __restrict__ S3,
    const uint4* __restrict__ KV3, const void* __restrict__ noise,
    void* __restrict__ out, const int* __restrict__ flag) {
  int d = blockIdx.x * 256 + threadIdx.x;
  if (d >= N_NODES) return;
  int base = off[d];
  int deg = off[d + 1] - base;
  float q0 = Q3[d * 4], q1 = Q3[d * 4 + 1], q2 = Q3[d * 4 + 2];
  const float isq = 0.57735026919f;  // 1/sqrt(3)
  // pass 1: max score
  float m = -1e30f;
  for (int j = 0; j < deg; ++j) {
    int src = csr[base + j];
    uint4 kv = KV3[src];
    float sc = (q0 * lo16(kv.x) + q1 * lo16(kv.y) + q2 * lo16(kv.z)) * isq;
    m = fmaxf(m, fminf(fmaxf(sc, -60.f), 60.f));
  }
  // pass 2: exp + weighted sums (independent FMAs, loads L2-hot)
  float ssum = 0.f, a0 = 0.f, a1 = 0.f, a2 = 0.f;
  for (int j = 0; j < deg; ++j) {
    int src = csr[base + j];
    uint4 kv = KV3[src];
    float sc = (q0 * lo16(kv.x) + q1 * lo16(kv.y) + q2 * lo16(kv.z)) * isq;
    float al = __expf(fminf(fmaxf(sc, -60.f), 60.f) - m);
    ssum += al;
    a0 += al * hi16(kv.x);
    a1 += al * hi16(kv.y);
    a2 += al * hi16(kv.z);
  }
  float inv = 1.f / (ssum + 1e-16f);
  int isbf = *flag;
  float n0, n1, n2;
  if (isbf) {
    const unsigned short* nu = (const unsigned short*)noise;
    n0 = bf2f(nu[d * 3 + 0]);
    n1 = bf2f(nu[d * 3 + 1]);
    n2 = bf2f(nu[d * 3 + 2]);
  } else {
    const float* nf = (const float*)noise;
    n0 = nf[d * 3 + 0];
    n1 = nf[d * 3 + 1];
    n2 = nf[d * 3 + 2];
  }
  float r0 = a0 * inv + S3[d * 4 + 0] + 0.1f * n0;
  float r1 = a1 * inv + S3[d * 4 + 1] + 0.1f * n1;
  float r2 = a2 * inv + S3[d * 4 + 2] + 0.1f * n2;
  if (isbf) {
    unsigned short* ou = (unsigned short*)out;
    ou[d * 3 + 0] = f2bf(r0);
    ou[d * 3 + 1] = f2bf(r1);
    ou[d * 3 + 2] = f2bf(r2);
  } else {
    float* of = (float*)out;
    of[d * 3 + 0] = r0;
    of[d * 3 + 1] = r1;
    of[d * 3 + 2] = r2;
  }
}

// ---------------- launch ----------------

extern "C" void kernel_launch(void* const* d_in, const int* in_sizes, int n_in,
                              void* d_out, int out_size, void* d_ws, size_t ws_size,
                              hipStream_t stream) {
  const int* ei = (const int*)d_in[1];
  const int* srcs = ei;
  const int* dsts = ei + N_EDGES;

  // Workspace (NEED = 51668480 B, proven available in round 3):
  //   off @0 | csr @400128 | h @13200128 (bf16) | kvbase @26000128:
  //     Kt bf16 [N][64] @ +0 (12.8MB), Vt bf16 [N][64] @ +12800000
  //     (aliases CSR scratch pre-layer-1; Q3/S3/KV3 in layer 3)
  //   wb @51600128 | flag @51668352
  char* w = (char*)d_ws;
  int* off = (int*)w;
  int* csr = (int*)(w + 400128);
  unsigned short* h = (unsigned short*)(w + 13200128);
  char* kvbase = w + 26000128;
  unsigned short* Kt = (unsigned short*)kvbase;
  unsigned short* Vt = (unsigned short*)(kvbase + 12800000);
  int* deg = (int*)kvbase;
  int* cursor = (int*)(kvbase + 524288);
  int* bsum = (int*)(kvbase + 1048576);
  int* bpref = (int*)(kvbase + 1056768);
  float* Q3 = (float*)kvbase;
  float* S3 = (float*)(kvbase + 2097152);
  uint4* KV3 = (uint4*)(kvbase + 4194304);
  unsigned short* wb = (unsigned short*)(w + 51600128);
  int* flag = (int*)(w + 51668352);
  const size_t NEED = 51668480;
  if (ws_size < NEED) return;

  unsigned short *Wb[3][4], *Bb[3][4];
  CvtArgs ca;
  {
    int o = 0, idx = 0;
    for (int l = 0; l < 3; ++l) {
      int dout = (l == 2) ? 3 : 64;
      for (int p = 0; p < 4; ++p) {
        ca.src[idx] = d_in[3 + l * 8 + p * 2];
        ca.dstoff[idx] = o;
        ca.n[idx] = 64 * dout;
        Wb[l][p] = wb + o;
        o += 64 * dout;
        idx++;
        ca.src[idx] = d_in[3 + l * 8 + p * 2 + 1];
        ca.dstoff[idx] = o;
        ca.n[idx] = dout;
        Bb[l][p] = wb + o;
        o += dout;
        idx++;
      }
    }
  }

  k_detect<<<1, 256, 0, stream>>>((const unsigned short*)d_in[0], flag);
  k_cvt_w<<<24, 256, 0, stream>>>(ca, wb, flag);
  k_cvt_x<<<N_NODES * 64 / 256, 256, 0, stream>>>(d_in[0], h, flag);

  k_zero<<<NB, 256, 0, stream>>>(deg, N_NODES);
  k_hist<<<N_EDGES / 256, 256, 0, stream>>>(dsts, deg);
  k_scan1<<<NB, 256, 0, stream>>>(deg, bsum);
  k_scan2<<<1, 512, 0, stream>>>(bsum, bpref, off + N_NODES);
  k_scan3<<<NB, 256, 0, stream>>>(deg, bpref, off, cursor);
  k_scatter<<<N_EDGES / 256, 256, 0, stream>>>(srcs, dsts, cursor, csr);

  const int gw = N_NODES / 4;  // 25000 blocks x 4 waves
  // layer 1
  k_gemmkv<<<gw, 256, 0, stream>>>(h, Wb[0][1], Bb[0][1], Wb[0][2], Bb[0][2], Kt, Vt);
  k_edge64<false><<<gw, 256, 0, stream>>>(off, csr, h, Wb[0][0], Bb[0][0],
                                          Wb[0][3], Bb[0][3], Kt, Vt, h);
  // layer 2
  k_gemmkv<<<gw, 256, 0, stream>>>(h, Wb[1][1], Bb[1][1], Wb[1][2], Bb[1][2], Kt, Vt);
  k_edge64<true><<<gw, 256, 0, stream>>>(off, csr, h, Wb[1][0], Bb[1][0],
                                         Wb[1][3], Bb[1][3], Kt, Vt, h);
  // layer 3
  k_gemm3<<<NB, 256, 0, stream>>>(h, Wb[2][0], Bb[2][0], Wb[2][1], Bb[2][1],
                                  Wb[2][2], Bb[2][2], Wb[2][3], Bb[2][3], Q3, S3, KV3);
  k_edge3<<<NB, 256, 0, stream>>>(off, csr, Q3, S3, KV3, d_in[2], d_out, flag);
}